// Round 1
// baseline (272.448 us; speedup 1.0000x reference)
//
#include <hip/hip_runtime.h>

typedef unsigned short u16;
typedef unsigned int   u32;

typedef __bf16 bf16x8 __attribute__((ext_vector_type(8)));
typedef float  f32x4  __attribute__((ext_vector_type(4)));

typedef const __attribute__((address_space(1))) void* gas_ptr;
typedef __attribute__((address_space(3))) void* las_ptr;

__device__ __forceinline__ u16 f2bf(float f) {
  u32 u = __builtin_bit_cast(u32, f);
  u += 0x7fffu + ((u >> 16) & 1u);
  return (u16)(u >> 16);
}
__device__ __forceinline__ float bf2f(u16 u) {
  return __builtin_bit_cast(float, ((u32)u) << 16);
}

// ---------------------------------------------------------------------------
// Kernel 1: BatchNorm over F-channels (stats over B,E) + bf16 cast.
// One block per f. x: [8][1024][1024] f32. Out xn: [8192][1024] bf16 (row = b*F+f).
// ---------------------------------------------------------------------------
__global__ __launch_bounds__(256) void bn_norm_kernel(
    const float* __restrict__ x, const float* __restrict__ gamma,
    const float* __restrict__ beta, u16* __restrict__ xn) {
  const int F = 1024, E = 1024;
  int f = blockIdx.x;
  __shared__ float sh[8192];
  __shared__ float ps[4], pq[4], sc[2];

  const float* xf = x + (size_t)f * E;
  float ls = 0.f, lq = 0.f;
  for (int i = threadIdx.x; i < 8192; i += 256) {
    int b = i >> 10, e = i & 1023;
    float v = xf[(size_t)b * F * E + e];
    sh[i] = v;
    ls += v;
    lq += v * v;
  }
  #pragma unroll
  for (int o = 32; o > 0; o >>= 1) {
    ls += __shfl_down(ls, o, 64);
    lq += __shfl_down(lq, o, 64);
  }
  int w = threadIdx.x >> 6;
  if ((threadIdx.x & 63) == 0) { ps[w] = ls; pq[w] = lq; }
  __syncthreads();
  if (threadIdx.x == 0) {
    float s = ps[0] + ps[1] + ps[2] + ps[3];
    float q = pq[0] + pq[1] + pq[2] + pq[3];
    float mean = s * (1.f / 8192.f);
    float var = q * (1.f / 8192.f) - mean * mean;
    float scale = gamma[f] * rsqrtf(var + 1e-5f);
    sc[0] = scale;
    sc[1] = beta[f] - mean * scale;
  }
  __syncthreads();
  float scale = sc[0], shift = sc[1];
  for (int i = threadIdx.x; i < 8192; i += 256) {
    int b = i >> 10, e = i & 1023;
    xn[((size_t)(b * F + f)) * E + e] = f2bf(sh[i] * scale + shift);
  }
}

// ---------------------------------------------------------------------------
// Kernel 2: W_qkv f32 -> bf16
// ---------------------------------------------------------------------------
__global__ __launch_bounds__(256) void wconv_kernel(
    const float* __restrict__ W, u16* __restrict__ Wb) {
  const int total = 3072 * 1024 / 4;
  for (int i = blockIdx.x * 256 + threadIdx.x; i < total; i += gridDim.x * 256) {
    float4 v = ((const float4*)W)[i];
    ushort4 o;
    o.x = f2bf(v.x); o.y = f2bf(v.y); o.z = f2bf(v.z); o.w = f2bf(v.w);
    ((ushort4*)Wb)[i] = o;
  }
}

// ---------------------------------------------------------------------------
// Kernel 3: GEMM  C[m][n] = sum_k A[m][k]*Bw[n][k] + bias[n]  (bf16 in/out, f32 acc)
// m97 structure: 128x128 tile, BK=32, 4 waves (2x2 of 64x64), global_load_lds w16.
// ---------------------------------------------------------------------------
__global__ __launch_bounds__(256) void gemm_qkv_kernel(
    const u16* __restrict__ A, const u16* __restrict__ Bw,
    const float* __restrict__ bias, u16* __restrict__ C) {
  const int K = 1024, N = 3072;
  __shared__ u16 As[128 * 32];
  __shared__ u16 Bs[128 * 32];

  int m0 = blockIdx.x * 128, n0 = blockIdx.y * 128;
  int t = threadIdx.x, lane = t & 63, w = t >> 6;
  int wr = w >> 1, wc = w & 1;
  int r = lane & 15, g = lane >> 4;

  int srow = t >> 2, scol = (t & 3) * 8;
  const u16* gA  = A  + (size_t)(m0 + srow) * K + scol;
  const u16* gA2 = gA + (size_t)64 * K;
  const u16* gB  = Bw + (size_t)(n0 + srow) * K + scol;
  const u16* gB2 = gB + (size_t)64 * K;
  u16* lA  = As + t * 8;
  u16* lA2 = As + 2048 + t * 8;
  u16* lB  = Bs + t * 8;
  u16* lB2 = Bs + 2048 + t * 8;

  f32x4 acc[4][4] = {};

  const u16* pA = As + (size_t)(wr * 64 + r) * 32 + g * 8;
  const u16* pB = Bs + (size_t)(wc * 64 + r) * 32 + g * 8;

  for (int k0 = 0; k0 < K; k0 += 32) {
    __builtin_amdgcn_global_load_lds((gas_ptr)gA,  (las_ptr)lA,  16, 0, 0);
    __builtin_amdgcn_global_load_lds((gas_ptr)gA2, (las_ptr)lA2, 16, 0, 0);
    __builtin_amdgcn_global_load_lds((gas_ptr)gB,  (las_ptr)lB,  16, 0, 0);
    __builtin_amdgcn_global_load_lds((gas_ptr)gB2, (las_ptr)lB2, 16, 0, 0);
    gA += 32; gA2 += 32; gB += 32; gB2 += 32;
    __syncthreads();

    bf16x8 af[4], bfr[4];
    #pragma unroll
    for (int mi = 0; mi < 4; ++mi)
      af[mi] = __builtin_bit_cast(bf16x8, *(const int4*)(pA + mi * 512));
    #pragma unroll
    for (int ni = 0; ni < 4; ++ni)
      bfr[ni] = __builtin_bit_cast(bf16x8, *(const int4*)(pB + ni * 512));
    #pragma unroll
    for (int mi = 0; mi < 4; ++mi)
      #pragma unroll
      for (int ni = 0; ni < 4; ++ni)
        acc[mi][ni] = __builtin_amdgcn_mfma_f32_16x16x32_bf16(af[mi], bfr[ni], acc[mi][ni], 0, 0, 0);
    __syncthreads();
  }

  #pragma unroll
  for (int ni = 0; ni < 4; ++ni) {
    int col = n0 + wc * 64 + ni * 16 + r;
    float bv = bias[col];
    #pragma unroll
    for (int mi = 0; mi < 4; ++mi) {
      int row = m0 + wr * 64 + mi * 16 + g * 4;
      #pragma unroll
      for (int j = 0; j < 4; ++j)
        C[(size_t)(row + j) * N + col] = f2bf(acc[mi][ni][j] + bv);
    }
  }
}

// ---------------------------------------------------------------------------
// Kernel 4: flash attention. 1 wave per block, 16 q-rows, 32-key kv-tiles.
// Swapped operands: S^T = mfma(K, Qs); acc^T = mfma(V^T, P^T).
// qkv: [8192][3072] bf16; per (b,h): Q at col h*192, K at +64, V at +128.
// out: [8][1024][1024] f32.
// ---------------------------------------------------------------------------
__global__ __launch_bounds__(64) void attn_kernel(
    const u16* __restrict__ qkv, float* __restrict__ out) {
  const int F = 1024, NQ = 3072;
  int q0 = blockIdx.x * 16;
  int bh = blockIdx.y;
  int b = bh >> 4, h = bh & 15;
  int lane = threadIdx.x;
  int q = lane & 15, g = lane >> 4;

  const u16* base = qkv + (size_t)b * F * NQ + h * 192;
  const u16* Kp = base + 64;
  const u16* Vp = base + 128;

  __shared__ u16  P_lds[16][40];   // padded: conflict-light
  __shared__ float outT[64][17];

  // Q fragment (B-operand), pre-scaled by 1/8 * log2(e) -> softmax in exp2 domain
  const float qscale = 0.125f * 1.4426950408889634f;
  bf16x8 Qf[2];
  {
    const u16* qp = base + (size_t)(q0 + q) * NQ;
    #pragma unroll
    for (int c = 0; c < 2; ++c) {
      union { int4 v; u16 u[8]; } uu;
      uu.v = *(const int4*)(qp + c * 32 + g * 8);
      union { u16 u[8]; bf16x8 v; } pu;
      #pragma unroll
      for (int j = 0; j < 8; ++j) pu.u[j] = f2bf(bf2f(uu.u[j]) * qscale);
      Qf[c] = pu.v;
    }
  }

  f32x4 accT[4] = {};
  float m = -INFINITY, lsum = 0.f;

  for (int kt = 0; kt < 32; ++kt) {
    int kb = kt * 32;
    // ---- S^T tile: [32 keys][16 q] as two 16x16 D-frags
    f32x4 s0 = {0.f, 0.f, 0.f, 0.f};
    f32x4 s1 = {0.f, 0.f, 0.f, 0.f};
    #pragma unroll
    for (int c = 0; c < 2; ++c) {
      int4 k0r = *(const int4*)(Kp + (size_t)(kb + q) * NQ + c * 32 + g * 8);
      int4 k1r = *(const int4*)(Kp + (size_t)(kb + 16 + q) * NQ + c * 32 + g * 8);
      s0 = __builtin_amdgcn_mfma_f32_16x16x32_bf16(__builtin_bit_cast(bf16x8, k0r), Qf[c], s0, 0, 0, 0);
      s1 = __builtin_amdgcn_mfma_f32_16x16x32_bf16(__builtin_bit_cast(bf16x8, k1r), Qf[c], s1, 0, 0, 0);
    }
    // ---- online softmax (exp2 domain). lane's 8 values all belong to q = lane&15.
    float tm = fmaxf(fmaxf(fmaxf(s0[0], s0[1]), fmaxf(s0[2], s0[3])),
                     fmaxf(fmaxf(s1[0], s1[1]), fmaxf(s1[2], s1[3])));
    tm = fmaxf(tm, __shfl_xor(tm, 16, 64));
    tm = fmaxf(tm, __shfl_xor(tm, 32, 64));
    float mnew = fmaxf(m, tm);
    float alpha = exp2f(m - mnew);
    float p0 = exp2f(s0[0] - mnew), p1 = exp2f(s0[1] - mnew);
    float p2 = exp2f(s0[2] - mnew), p3 = exp2f(s0[3] - mnew);
    float p4 = exp2f(s1[0] - mnew), p5 = exp2f(s1[1] - mnew);
    float p6 = exp2f(s1[2] - mnew), p7 = exp2f(s1[3] - mnew);
    float psum = ((p0 + p1) + (p2 + p3)) + ((p4 + p5) + (p6 + p7));
    psum += __shfl_xor(psum, 16, 64);
    psum += __shfl_xor(psum, 32, 64);
    lsum = lsum * alpha + psum;
    m = mnew;
    #pragma unroll
    for (int dt = 0; dt < 4; ++dt) {
      accT[dt][0] *= alpha; accT[dt][1] *= alpha;
      accT[dt][2] *= alpha; accT[dt][3] *= alpha;
    }
    // ---- P^T -> LDS (bf16), then read back as the PV B-operand
    *(u32*)&P_lds[q][g * 4]      = (u32)f2bf(p0) | ((u32)f2bf(p1) << 16);
    *(u32*)&P_lds[q][g * 4 + 2]  = (u32)f2bf(p2) | ((u32)f2bf(p3) << 16);
    *(u32*)&P_lds[q][16 + g * 4]     = (u32)f2bf(p4) | ((u32)f2bf(p5) << 16);
    *(u32*)&P_lds[q][16 + g * 4 + 2] = (u32)f2bf(p6) | ((u32)f2bf(p7) << 16);
    asm volatile("s_waitcnt lgkmcnt(0)" ::: "memory");
    bf16x8 pb = __builtin_bit_cast(bf16x8, *(const int4*)&P_lds[q][g * 8]);
    // ---- PV: acc^T[d][q] += V^T @ P^T
    #pragma unroll
    for (int dt = 0; dt < 4; ++dt) {
      union { u16 u[8]; bf16x8 v; } vf;
      #pragma unroll
      for (int jj = 0; jj < 8; ++jj)
        vf.u[jj] = Vp[(size_t)(kb + g * 8 + jj) * NQ + dt * 16 + q];
      accT[dt] = __builtin_amdgcn_mfma_f32_16x16x32_bf16(vf.v, pb, accT[dt], 0, 0, 0);
    }
  }

  // ---- epilogue: normalize, transpose via LDS, coalesced float4 stores
  float inv = 1.0f / lsum;
  #pragma unroll
  for (int dt = 0; dt < 4; ++dt) {
    outT[dt * 16 + g * 4 + 0][q] = accT[dt][0] * inv;
    outT[dt * 16 + g * 4 + 1][q] = accT[dt][1] * inv;
    outT[dt * 16 + g * 4 + 2][q] = accT[dt][2] * inv;
    outT[dt * 16 + g * 4 + 3][q] = accT[dt][3] * inv;
  }
  asm volatile("s_waitcnt lgkmcnt(0)" ::: "memory");
  int oq = lane >> 2, dc = (lane & 3) * 16;
  float* orow = out + (size_t)(b * F + q0 + oq) * 1024 + h * 64 + dc;
  #pragma unroll
  for (int c4 = 0; c4 < 4; ++c4) {
    float4 v;
    v.x = outT[dc + c4 * 4 + 0][oq];
    v.y = outT[dc + c4 * 4 + 1][oq];
    v.z = outT[dc + c4 * 4 + 2][oq];
    v.w = outT[dc + c4 * 4 + 3][oq];
    *(float4*)(orow + c4 * 4) = v;
  }
}

// ---------------------------------------------------------------------------
extern "C" void kernel_launch(void* const* d_in, const int* in_sizes, int n_in,
                              void* d_out, int out_size, void* d_ws, size_t ws_size,
                              hipStream_t stream) {
  const float* x     = (const float*)d_in[0];
  const float* gamma = (const float*)d_in[1];
  const float* beta  = (const float*)d_in[2];
  const float* W     = (const float*)d_in[3];
  const float* bias  = (const float*)d_in[4];
  float* out = (float*)d_out;

  char* ws = (char*)d_ws;
  u16* xn  = (u16*)ws;                                   // 8192*1024*2  = 16 MB
  u16* Wb  = (u16*)(ws + (size_t)16 * 1024 * 1024);      // 3072*1024*2  =  6 MB
  u16* qkv = (u16*)(ws + (size_t)22 * 1024 * 1024);      // 8192*3072*2  = 48 MB

  bn_norm_kernel<<<1024, 256, 0, stream>>>(x, gamma, beta, xn);
  wconv_kernel<<<768, 256, 0, stream>>>(W, Wb);
  gemm_qkv_kernel<<<dim3(64, 24), 256, 0, stream>>>(xn, Wb, bias, qkv);
  attn_kernel<<<dim3(64, 128), 64, 0, stream>>>(qkv, out);
}